// Round 3
// baseline (316.469 us; speedup 1.0000x reference)
//
#include <hip/hip_runtime.h>
#include <math.h>

#define T1 17
#define NN 2048
#define DIN 9
#define CC 8
#define KK 5
#define PASS 1024
#define LPAD 1032   // PASS + 8: bank-spread for per-quarter plane writes
#define BT 512

#define XD_BYTES (T1 * NN * CC * 4)

__device__ __forceinline__ bool lexlt(float d1, int j1, float d2, int j2) {
  return d1 < d2 || (d1 == d2 && j1 < j2);
}

// ---------------------------------------------------------------------------
// Prep (1 block x 1024): bitmasks, ordered compaction of valid donors
// (present at t=16), donor masks, observed column means at t=16.
__global__ __launch_bounds__(1024) void prep_kernel(
    const float* __restrict__ x_all, const int* __restrict__ mask,
    unsigned* __restrict__ pm, int* __restrict__ dlist,
    unsigned* __restrict__ pmd, float* __restrict__ colmean,
    int* __restrict__ ndon_p) {
  __shared__ unsigned long long bal[2][16];
  __shared__ int pre[33];
  __shared__ float ssum[1024][CC];  // 32KB
  const int tid = threadIdx.x;
  const int lane = tid & 63, w = tid >> 6;

  unsigned m0 = 0, m1 = 0;
#pragma unroll
  for (int t = 0; t < T1; ++t) {
    m0 |= (mask[t * NN + tid] == 0 ? 1u : 0u) << t;
    m1 |= (mask[t * NN + tid + 1024] == 0 ? 1u : 0u) << t;
  }
  pm[tid] = m0;
  pm[tid + 1024] = m1;
  const bool v0 = (m0 >> 16) & 1u, v1 = (m1 >> 16) & 1u;
  const unsigned long long b0 = __ballot(v0), b1 = __ballot(v1);
  if (lane == 0) { bal[0][w] = b0; bal[1][w] = b1; }

  float s[CC];
#pragma unroll
  for (int c = 0; c < CC; ++c) s[c] = 0.f;
  if (v0) {
#pragma unroll
    for (int c = 0; c < CC; ++c) s[c] += x_all[((size_t)16 * NN + tid) * DIN + c];
  }
  if (v1) {
#pragma unroll
    for (int c = 0; c < CC; ++c) s[c] += x_all[((size_t)16 * NN + tid + 1024) * DIN + c];
  }
#pragma unroll
  for (int c = 0; c < CC; ++c) ssum[tid][c] = s[c];
  __syncthreads();

  if (tid == 0) {
    int acc = 0;
    for (int h = 0; h < 2; ++h)
      for (int q = 0; q < 16; ++q) { pre[h * 16 + q] = acc; acc += __popcll(bal[h][q]); }
    pre[32] = acc;
    *ndon_p = acc;
  }
  __syncthreads();

  const unsigned long long ltm = (1ull << lane) - 1ull;
  if (v0) { const int p = pre[w] + (int)__popcll(b0 & ltm); dlist[p] = tid; pmd[p] = m0; }
  if (v1) { const int p = pre[16 + w] + (int)__popcll(b1 & ltm); dlist[p] = tid + 1024; pmd[p] = m1; }

  for (int off = 512; off > 0; off >>= 1) {
    if (tid < off) {
#pragma unroll
      for (int c = 0; c < CC; ++c) ssum[tid][c] += ssum[tid + off][c];
    }
    __syncthreads();
  }
  if (tid < CC) colmean[tid] = ssum[0][tid] / fmaxf((float)pre[32], 1.f);
}

// ---------------------------------------------------------------------------
// Pack donor data: xd[t][dn][c] = x_all[t][dlist[dn]][c]
__global__ void transpose_kernel(const float* __restrict__ x_all,
                                 const int* __restrict__ dlist,
                                 const int* __restrict__ ndon_p,
                                 float* __restrict__ xd) {
  const int u = blockIdx.x * 256 + threadIdx.x;
  if (u >= T1 * NN * CC) return;
  const int t = u / (NN * CC);
  const int rem = u % (NN * CC);
  const int dn = rem >> 3;
  const int c = rem & 7;
  if (dn < *ndon_p) xd[u] = x_all[((size_t)t * NN + dlist[dn]) * DIN + c];
}

// ---------------------------------------------------------------------------
// Main: one block (512 thr) per target row. thread = (dn_off in [0,128),
// quarter q -> 2 channels). 8 donor streams per thread, distances of a
// 1024-donor pass in padded LDS; per-channel wave does <=5 lex-min rounds.
__global__ __launch_bounds__(BT, 4) void knn_main(
    const float* __restrict__ x_all, const float* __restrict__ xd,
    const unsigned* __restrict__ pm, const unsigned* __restrict__ pmd,
    const int* __restrict__ ndon_p, const float* __restrict__ colmean,
    float* __restrict__ out) {
  __shared__ float sdist[CC][LPAD];  // 33KB
  const int tid = threadIdx.x;
  const int i = blockIdx.x;
  const unsigned mi = pm[i];

  if ((mi >> 16) & 1u) {  // present at t=16: passthrough
    if (tid < CC) out[i * CC + tid] = x_all[((size_t)16 * NN + i) * DIN + tid];
    return;
  }
  const int ndon = *ndon_p;
  const int qtr = tid & 3;        // channel quarter: channels c0, c0+1
  const int c0 = qtr * 2;
  const int dn_off = tid >> 2;    // [0,128)
  const int lane = tid & 63, w = tid >> 6;

  // Query registers, t = 0..15 only: bit16 of (mi & pmd) is always 0 here
  // (query missing at t=16), so t=16 contributes nothing to any distance.
  float q0[16], q1[16];
#pragma unroll
  for (int t = 0; t < 16; ++t) {
    q0[t] = x_all[((size_t)t * NN + i) * DIN + c0];
    q1[t] = x_all[((size_t)t * NN + i) * DIN + c0 + 1];
  }

  // Running top-5 (lex ascending (d, j)), wave-uniform after butterflies.
  float rd0 = INFINITY, rd1 = INFINITY, rd2 = INFINITY, rd3 = INFINITY, rd4 = INFINITY;
  int rj0 = 0x7FFFFFFF, rj1 = 0x7FFFFFFF, rj2 = 0x7FFFFFFF, rj3 = 0x7FFFFFFF, rj4 = 0x7FFFFFFF;

  for (int base = 0; base < ndon; base += PASS) {
    // ---- distance phase: 8 streams x 2 channels per thread ----
    float a0[8], a1[8];
    unsigned ms[8];
    int cnts[8];
#pragma unroll
    for (int s = 0; s < 8; ++s) {
      const int dn = base + dn_off + s * 128;
      const bool v = dn < ndon;
      ms[s] = v ? (mi & pmd[dn]) : 0u;
      cnts[s] = __popc(ms[s]);
      a0[s] = 0.f;
      a1[s] = 0.f;
    }
#pragma unroll
    for (int t = 0; t < 16; ++t) {
      const float qa = q0[t], qb = q1[t];
#pragma unroll
      for (int s = 0; s < 8; ++s) {
        const int dn = base + dn_off + s * 128;
        const float2 dv = *(const float2*)&xd[((size_t)t * NN + dn) * CC + c0];
        const float fl = (float)((ms[s] >> t) & 1u);
        float e;
        e = qa - dv.x; a0[s] = fmaf(e * e, fl, a0[s]);
        e = qb - dv.y; a1[s] = fmaf(e * e, fl, a1[s]);
      }
    }
#pragma unroll
    for (int s = 0; s < 8; ++s) {
      const int sl = dn_off + s * 128;
      float d0 = INFINITY, d1 = INFINITY;
      if (cnts[s] > 0) {
        const float sc = 17.f / (float)cnts[s];
        d0 = sqrtf(a0[s] * sc);
        d1 = sqrtf(a1[s] * sc);
      }
      sdist[c0][sl] = d0;
      sdist[c0 + 1][sl] = d1;
    }
    __syncthreads();

    // ---- selection: wave w handles channel w over this pass ----
    float d16[16];
#pragma unroll
    for (int u = 0; u < 4; ++u) {
      const float4 v4 = *(const float4*)&sdist[w][u * 256 + lane * 4];
      d16[u * 4 + 0] = v4.x;
      d16[u * 4 + 1] = v4.y;
      d16[u * 4 + 2] = v4.z;
      d16[u * 4 + 3] = v4.w;
    }
    float pd = -INFINITY;
    int pj = -1;
    for (int k = 0; k < KK; ++k) {
      float bd = INFINITY;
      int bj = 0x7FFFFFFF;
#pragma unroll
      for (int u = 0; u < 16; ++u) {
        const int j = base + (u >> 2) * 256 + lane * 4 + (u & 3);
        const float d = d16[u];
        const bool gt = (d > pd) || (d == pd && j > pj);
        const bool lt = (d < bd) || (d == bd && j < bj);
        if (gt && lt) { bd = d; bj = j; }
      }
#pragma unroll
      for (int off = 32; off > 0; off >>= 1) {
        const float od = __shfl_xor(bd, off);
        const int oj = __shfl_xor(bj, off);
        if (od < bd || (od == bd && oj < bj)) { bd = od; bj = oj; }
      }
      if (!lexlt(bd, bj, rd4, rj4)) break;  // wave-uniform
      rd4 = bd; rj4 = bj;
      if (lexlt(rd4, rj4, rd3, rj3)) {
        float td = rd3; rd3 = rd4; rd4 = td; int tj = rj3; rj3 = rj4; rj4 = tj;
      }
      if (lexlt(rd3, rj3, rd2, rj2)) {
        float td = rd2; rd2 = rd3; rd3 = td; int tj = rj2; rj2 = rj3; rj3 = tj;
      }
      if (lexlt(rd2, rj2, rd1, rj1)) {
        float td = rd1; rd1 = rd2; rd2 = td; int tj = rj1; rj1 = rj2; rj2 = tj;
      }
      if (lexlt(rd1, rj1, rd0, rj0)) {
        float td = rd0; rd0 = rd1; rd1 = td; int tj = rj0; rj0 = rj1; rj1 = tj;
      }
      pd = bd;
      pj = bj;
    }
    if (base + PASS < ndon) __syncthreads();  // protect sdist before overwrite
  }

  // ---- output: sum donor values in ascending (d, j) order ----
  const float* __restrict__ xd16 = xd + (size_t)16 * NN * CC;
  float sum = 0.f;
  int cn = 0;
  if (rd0 < INFINITY) { sum += xd16[rj0 * CC + w]; ++cn; }
  if (rd1 < INFINITY) { sum += xd16[rj1 * CC + w]; ++cn; }
  if (rd2 < INFINITY) { sum += xd16[rj2 * CC + w]; ++cn; }
  if (rd3 < INFINITY) { sum += xd16[rj3 * CC + w]; ++cn; }
  if (rd4 < INFINITY) { sum += xd16[rj4 * CC + w]; ++cn; }
  if (lane == 0) out[i * CC + w] = (cn > 0) ? sum / (float)cn : colmean[w];
}

// ---------------------------------------------------------------------------
extern "C" void kernel_launch(void* const* d_in, const int* in_sizes, int n_in,
                              void* d_out, int out_size, void* d_ws, size_t ws_size,
                              hipStream_t stream) {
  const float* x_all = (const float*)d_in[0];  // [17, 2048, 9] f32
  const int* mask = (const int*)d_in[1];       // [17, 2048] i32
  float* out = (float*)d_out;                  // [2048, 8] f32

  char* ws = (char*)d_ws;
  float* xd = (float*)ws;
  unsigned* pm = (unsigned*)(ws + XD_BYTES);
  int* dlist = (int*)(ws + XD_BYTES + NN * 4);
  unsigned* pmd = (unsigned*)(ws + XD_BYTES + NN * 8);
  float* colmean = (float*)(ws + XD_BYTES + NN * 12);
  int* ndon_p = (int*)(ws + XD_BYTES + NN * 12 + CC * 4);

  prep_kernel<<<1, 1024, 0, stream>>>(x_all, mask, pm, dlist, pmd, colmean, ndon_p);
  transpose_kernel<<<(T1 * NN * CC + 255) / 256, 256, 0, stream>>>(x_all, dlist, ndon_p, xd);
  knn_main<<<NN, BT, 0, stream>>>(x_all, xd, pm, pmd, ndon_p, colmean, out);
}

// Round 4
// 55.726 us; speedup vs baseline: 5.6791x; 5.6791x over previous
//
#include <hip/hip_runtime.h>
#include <math.h>

#define T1 17
#define NN 2048
#define DIN 9
#define CC 8
#define KK 5
#define NSTR 5                 // donor streams per thread (512-thr block)
#define NDCAP (NSTR * 256)     // 1280 donor slots (E[ndon]=1024, +11 sigma)
#define LPAD (NDCAP + 8)       // plane width, bank-safe
#define NU (NDCAP / 64)        // 20 cached distances per lane

#define XD_BYTES (T1 * NN * CC * 4)

// ---------------------------------------------------------------------------
// Prep (1 block x 1024): bitmasks, ordered compaction of valid donors
// (present at t=16), donor masks, observed column means at t=16.
__global__ __launch_bounds__(1024) void prep_kernel(
    const float* __restrict__ x_all, const int* __restrict__ mask,
    unsigned* __restrict__ pm, int* __restrict__ dlist,
    unsigned* __restrict__ pmd, float* __restrict__ colmean,
    int* __restrict__ ndon_p) {
  __shared__ unsigned long long bal[2][16];
  __shared__ int pre[33];
  __shared__ float ssum[1024][CC];  // 32KB
  const int tid = threadIdx.x;
  const int lane = tid & 63, w = tid >> 6;

  unsigned m0 = 0, m1 = 0;
#pragma unroll
  for (int t = 0; t < T1; ++t) {
    m0 |= (mask[t * NN + tid] == 0 ? 1u : 0u) << t;
    m1 |= (mask[t * NN + tid + 1024] == 0 ? 1u : 0u) << t;
  }
  pm[tid] = m0;
  pm[tid + 1024] = m1;
  const bool v0 = (m0 >> 16) & 1u, v1 = (m1 >> 16) & 1u;
  const unsigned long long b0 = __ballot(v0), b1 = __ballot(v1);
  if (lane == 0) { bal[0][w] = b0; bal[1][w] = b1; }

  float s[CC];
#pragma unroll
  for (int c = 0; c < CC; ++c) s[c] = 0.f;
  if (v0) {
#pragma unroll
    for (int c = 0; c < CC; ++c) s[c] += x_all[((size_t)16 * NN + tid) * DIN + c];
  }
  if (v1) {
#pragma unroll
    for (int c = 0; c < CC; ++c) s[c] += x_all[((size_t)16 * NN + tid + 1024) * DIN + c];
  }
#pragma unroll
  for (int c = 0; c < CC; ++c) ssum[tid][c] = s[c];
  __syncthreads();

  if (tid == 0) {
    int acc = 0;
    for (int h = 0; h < 2; ++h)
      for (int q = 0; q < 16; ++q) { pre[h * 16 + q] = acc; acc += __popcll(bal[h][q]); }
    pre[32] = acc;
    *ndon_p = acc;
  }
  __syncthreads();

  const unsigned long long ltm = (1ull << lane) - 1ull;
  if (v0) { const int p = pre[w] + (int)__popcll(b0 & ltm); dlist[p] = tid; pmd[p] = m0; }
  if (v1) { const int p = pre[16 + w] + (int)__popcll(b1 & ltm); dlist[p] = tid + 1024; pmd[p] = m1; }

  for (int off = 512; off > 0; off >>= 1) {
    if (tid < off) {
#pragma unroll
      for (int c = 0; c < CC; ++c) ssum[tid][c] += ssum[tid + off][c];
    }
    __syncthreads();
  }
  if (tid < CC) colmean[tid] = ssum[0][tid] / fmaxf((float)pre[32], 1.f);
}

// ---------------------------------------------------------------------------
// Pack donor data: xd[t][dn][c] = x_all[t][dlist[dn]][c]
__global__ void transpose_kernel(const float* __restrict__ x_all,
                                 const int* __restrict__ dlist,
                                 const int* __restrict__ ndon_p,
                                 float* __restrict__ xd) {
  const int u = blockIdx.x * 256 + threadIdx.x;
  if (u >= T1 * NN * CC) return;
  const int t = u / (NN * CC);
  const int rem = u % (NN * CC);
  const int dn = rem >> 3;
  const int c = rem & 7;
  if (dn < *ndon_p) xd[u] = x_all[((size_t)t * NN + dlist[dn]) * DIN + c];
}

// ---------------------------------------------------------------------------
// Main: one block (512 thr) per target row. Thread = (dg in [0,256), channel
// half qd). Stream-outer distance loop keeps only 4 accumulators live.
// Selection: wave w = channel w, register-cached 20 values, 5 extraction
// rounds (bit-exact, lowest-index ties == numpy top_k).
__global__ __launch_bounds__(512, 3) void knn_main(
    const float* __restrict__ x_all, const float* __restrict__ xd,
    const unsigned* __restrict__ pm, const unsigned* __restrict__ pmd,
    const int* __restrict__ ndon_p, const float* __restrict__ colmean,
    float* __restrict__ out) {
  __shared__ float sdist[CC][LPAD];  // 41,216 B
  __shared__ float qlds[16][CC];
  __shared__ float rcp17[32];
  const int tid = threadIdx.x;
  const int i = blockIdx.x;
  const unsigned mi = pm[i];

  if ((mi >> 16) & 1u) {  // present at t=16: passthrough
    if (tid < CC) out[i * CC + tid] = x_all[((size_t)16 * NN + i) * DIN + tid];
    return;
  }
  const int ndon = *ndon_p;

  if (tid < 32) rcp17[tid] = 17.f / (float)tid;  // [0] = inf, guarded
  if (tid < 16 * CC)
    qlds[tid >> 3][tid & 7] = x_all[((size_t)(tid >> 3) * NN + i) * DIN + (tid & 7)];
  __syncthreads();

  const int qd = tid & 1;       // channel half -> c0..c0+3
  const int c0 = qd * 4;
  const int dg = tid >> 1;      // [0,256)
  const int lane = tid & 63;
  const int w = tid >> 6;       // wave id = channel

  // ---- distance phase: stream-outer, 4 live accumulators ----
  for (int s = 0; s < NSTR; ++s) {
    const int dn = dg + 256 * s;
    float a0 = 0.f, a1 = 0.f, a2 = 0.f, a3 = 0.f;
    unsigned msk = 0u;
    if (256 * s < ndon) {
      msk = (dn < ndon) ? (mi & pmd[dn]) : 0u;
#pragma unroll
      for (int t = 0; t < 16; ++t) {  // t=16 never contributes (query missing)
        const float4 qv = *(const float4*)&qlds[t][c0];
        const float4 dv = *(const float4*)&xd[((size_t)t * NN + dn) * CC + c0];
        const float fl = (float)((msk >> t) & 1u);
        float e;
        e = qv.x - dv.x; a0 = fmaf(e * e, fl, a0);
        e = qv.y - dv.y; a1 = fmaf(e * e, fl, a1);
        e = qv.z - dv.z; a2 = fmaf(e * e, fl, a2);
        e = qv.w - dv.w; a3 = fmaf(e * e, fl, a3);
      }
    }
    const int cnt = __popc(msk);
    const float sc = rcp17[cnt & 31];
    const bool ok = cnt > 0;
    sdist[c0 + 0][dn] = ok ? sqrtf(a0 * sc) : INFINITY;
    sdist[c0 + 1][dn] = ok ? sqrtf(a1 * sc) : INFINITY;
    sdist[c0 + 2][dn] = ok ? sqrtf(a2 * sc) : INFINITY;
    sdist[c0 + 3][dn] = ok ? sqrtf(a3 * sc) : INFINITY;
  }
  __syncthreads();

  // ---- selection: wave w handles channel w ----
  float dvr[NU];
#pragma unroll
  for (int u = 0; u < NU; ++u) dvr[u] = sdist[w][u * 64 + lane];

  float sum = 0.f;
  int cn = 0;
#pragma unroll
  for (int k = 0; k < KK; ++k) {
    float g = dvr[0];
#pragma unroll
    for (int u = 1; u < NU; ++u) g = fminf(g, dvr[u]);
#pragma unroll
    for (int off = 32; off > 0; off >>= 1) g = fminf(g, __shfl_xor(g, off));
    if (g < INFINITY) {  // wave-uniform
      int jloc = 0x7FFFFFFF;
#pragma unroll
      for (int u = NU - 1; u >= 0; --u)
        if (dvr[u] == g) jloc = u * 64 + lane;  // lowest u => lowest index
      int jg = jloc;
#pragma unroll
      for (int off = 32; off > 0; off >>= 1) jg = min(jg, __shfl_xor(jg, off));
      const int jgs = __builtin_amdgcn_readfirstlane(jg);
      const int tu = jgs >> 6, tl = jgs & 63;
#pragma unroll
      for (int u = 0; u < NU; ++u)
        if (u == tu) dvr[u] = (lane == tl) ? INFINITY : dvr[u];
      sum += xd[((size_t)16 * NN + jgs) * CC + w];  // ascending (d,j) order
      ++cn;
    }
  }
  if (lane == 0) out[i * CC + w] = (cn > 0) ? sum / (float)cn : colmean[w];
}

// ---------------------------------------------------------------------------
extern "C" void kernel_launch(void* const* d_in, const int* in_sizes, int n_in,
                              void* d_out, int out_size, void* d_ws, size_t ws_size,
                              hipStream_t stream) {
  const float* x_all = (const float*)d_in[0];  // [17, 2048, 9] f32
  const int* mask = (const int*)d_in[1];       // [17, 2048] i32
  float* out = (float*)d_out;                  // [2048, 8] f32

  char* ws = (char*)d_ws;
  float* xd = (float*)ws;
  unsigned* pm = (unsigned*)(ws + XD_BYTES);
  int* dlist = (int*)(ws + XD_BYTES + NN * 4);
  unsigned* pmd = (unsigned*)(ws + XD_BYTES + NN * 8);
  float* colmean = (float*)(ws + XD_BYTES + NN * 12);
  int* ndon_p = (int*)(ws + XD_BYTES + NN * 12 + CC * 4);

  prep_kernel<<<1, 1024, 0, stream>>>(x_all, mask, pm, dlist, pmd, colmean, ndon_p);
  transpose_kernel<<<(T1 * NN * CC + 255) / 256, 256, 0, stream>>>(x_all, dlist, ndon_p, xd);
  knn_main<<<NN, 512, 0, stream>>>(x_all, xd, pm, pmd, ndon_p, colmean, out);
}

// Round 5
// 47.208 us; speedup vs baseline: 6.7037x; 1.1804x over previous
//
#include <hip/hip_runtime.h>
#include <math.h>

#define T1 17
#define NN 2048
#define DIN 9
#define CC 8
#define KK 5
#define NSTR 5                 // donor streams per thread (512-thr block)
#define NDCAP (NSTR * 256)     // 1280 donor slots (E[ndon]=1024, +11 sigma)
#define NQCAP 1280             // query slots (nq = 2048 - ndon <= 1280)
#define LPAD (NDCAP + 8)
#define NU (NDCAP / 64)        // 20 cached distances per lane

#define XD_BYTES (T1 * NN * CC * 4)

// ---------------------------------------------------------------------------
// Prep (1 block x 1024): bitmasks, ordered compaction of donors (present at
// t=16) AND queries (missing at t=16), colmean, and passthrough output rows.
__global__ __launch_bounds__(1024) void prep_kernel(
    const float* __restrict__ x_all, const int* __restrict__ mask,
    unsigned* __restrict__ pm, int* __restrict__ dlist,
    unsigned* __restrict__ pmd, int* __restrict__ qlist,
    float* __restrict__ colmean, int* __restrict__ cnts,
    float* __restrict__ out) {
  __shared__ unsigned long long dbal[32];
  __shared__ int dpre[33], qpre[33];
  __shared__ float wsum[16][CC];
  const int tid = threadIdx.x;
  const int lane = tid & 63, w = tid >> 6;  // w in [0,16)

  unsigned m0 = 0, m1 = 0;
#pragma unroll
  for (int t = 0; t < T1; ++t) {
    m0 |= (mask[t * NN + tid] == 0 ? 1u : 0u) << t;
    m1 |= (mask[t * NN + tid + 1024] == 0 ? 1u : 0u) << t;
  }
  pm[tid] = m0;
  pm[tid + 1024] = m1;
  const bool v0 = (m0 >> 16) & 1u, v1 = (m1 >> 16) & 1u;
  const unsigned long long b0 = __ballot(v0), b1 = __ballot(v1);
  if (lane == 0) { dbal[w] = b0; dbal[16 + w] = b1; }

  // passthrough writes + colmean partials
  float s[CC];
#pragma unroll
  for (int c = 0; c < CC; ++c) s[c] = 0.f;
  if (v0) {
    const float* row = x_all + ((size_t)16 * NN + tid) * DIN;
#pragma unroll
    for (int c = 0; c < CC; ++c) { const float v = row[c]; s[c] = v; out[tid * CC + c] = v; }
  }
  if (v1) {
    const float* row = x_all + ((size_t)16 * NN + tid + 1024) * DIN;
#pragma unroll
    for (int c = 0; c < CC; ++c) { const float v = row[c]; s[c] += v; out[(tid + 1024) * CC + c] = v; }
  }
#pragma unroll
  for (int off = 32; off > 0; off >>= 1) {
#pragma unroll
    for (int c = 0; c < CC; ++c) s[c] += __shfl_down(s[c], off);
  }
  if (lane == 0) {
#pragma unroll
    for (int c = 0; c < CC; ++c) wsum[w][c] = s[c];
  }
  __syncthreads();

  if (tid == 0) {
    int a = 0, b = 0;
    for (int g = 0; g < 32; ++g) {
      dpre[g] = a;
      qpre[g] = b;
      const int p = (int)__popcll(dbal[g]);
      a += p;
      b += 64 - p;
    }
    dpre[32] = a;
    qpre[32] = b;
    cnts[0] = a;  // ndon
    cnts[1] = b;  // nq
  }
  __syncthreads();

  const unsigned long long ltm = (1ull << lane) - 1ull;  // lane 0 -> 0
  if (v0) {
    const int p = dpre[w] + (int)__popcll(b0 & ltm);
    dlist[p] = tid; pmd[p] = m0;
  } else {
    const int p = qpre[w] + (int)__popcll((~b0) & ltm);
    qlist[p] = tid;
  }
  if (v1) {
    const int p = dpre[16 + w] + (int)__popcll(b1 & ltm);
    dlist[p] = tid + 1024; pmd[p] = m1;
  } else {
    const int p = qpre[16 + w] + (int)__popcll((~b1) & ltm);
    qlist[p] = tid + 1024;
  }

  if (tid < CC) {
    float tot = 0.f;
#pragma unroll
    for (int ww = 0; ww < 16; ++ww) tot += wsum[ww][tid];
    colmean[tid] = tot / fmaxf((float)dpre[32], 1.f);
  }
}

// ---------------------------------------------------------------------------
// Pack donor data: xd[t][dn][c] = x_all[t][dlist[dn]][c]
__global__ void transpose_kernel(const float* __restrict__ x_all,
                                 const int* __restrict__ dlist,
                                 const int* __restrict__ cnts,
                                 float* __restrict__ xd) {
  const int u = blockIdx.x * 256 + threadIdx.x;
  if (u >= T1 * NN * CC) return;
  const int t = u / (NN * CC);
  const int rem = u % (NN * CC);
  const int dn = rem >> 3;
  const int c = rem & 7;
  if (dn < cnts[0]) xd[u] = x_all[((size_t)t * NN + dlist[dn]) * DIN + c];
}

// ---------------------------------------------------------------------------
// Main: one block (512 thr) per QUERY row (compacted). Wave-uniform sparse
// t-loop over set bits of mi (terms with mi_t=0 contribute exactly 0).
// Selection: wave w = channel w, register-cached 20 values, 5 extraction
// rounds (bit-exact, lowest-index ties == numpy top_k).
__global__ __launch_bounds__(512, 3) void knn_main(
    const float* __restrict__ x_all, const float* __restrict__ xd,
    const unsigned* __restrict__ pm, const unsigned* __restrict__ pmd,
    const int* __restrict__ qlist, const int* __restrict__ cnts,
    const float* __restrict__ colmean, float* __restrict__ out) {
  __shared__ float sdist[CC][LPAD];  // 41,216 B
  __shared__ float qlds[16][CC];
  __shared__ float rcp17[32];
  const int nq = cnts[1];
  const int bid = blockIdx.x;
  if (bid >= nq) return;
  const int i = qlist[bid];          // missing at t=16 by construction
  const int ndon = cnts[0];
  const unsigned mi = pm[i];         // bit 16 == 0
  const int tid = threadIdx.x;

  if (tid < 32) rcp17[tid] = 17.f / (float)tid;  // [0] = inf, guarded
  if (tid < 16 * CC)
    qlds[tid >> 3][tid & 7] = x_all[((size_t)(tid >> 3) * NN + i) * DIN + (tid & 7)];
  __syncthreads();

  const int qd = tid & 1;       // channel half -> c0..c0+3
  const int c0 = qd * 4;
  const int dg = tid >> 1;      // [0,256)
  const int lane = tid & 63;
  const int w = tid >> 6;       // wave id = channel

  // ---- distance phase: sparse t over mi's set bits (wave-uniform) ----
  for (int s = 0; s < NSTR; ++s) {
    const int dn = dg + 256 * s;
    float a0 = 0.f, a1 = 0.f, a2 = 0.f, a3 = 0.f;
    unsigned msk = 0u;
    if (256 * s < ndon) {
      msk = (dn < ndon) ? (mi & pmd[dn]) : 0u;
      const float* dbase = xd + (size_t)dn * CC + c0;
      for (unsigned tm = mi & 0xFFFFu; tm; tm &= tm - 1u) {
        const int t = __ffs(tm) - 1;
        const float4 qv = *(const float4*)&qlds[t][c0];
        const float4 dv = *(const float4*)(dbase + (size_t)t * (NN * CC));
        const float fl = (float)((msk >> t) & 1u);
        float e;
        e = qv.x - dv.x; a0 = fmaf(e * e, fl, a0);
        e = qv.y - dv.y; a1 = fmaf(e * e, fl, a1);
        e = qv.z - dv.z; a2 = fmaf(e * e, fl, a2);
        e = qv.w - dv.w; a3 = fmaf(e * e, fl, a3);
      }
    }
    const int cnt = __popc(msk);
    const float sc = rcp17[cnt & 31];
    const bool ok = cnt > 0;
    sdist[c0 + 0][dn] = ok ? sqrtf(a0 * sc) : INFINITY;
    sdist[c0 + 1][dn] = ok ? sqrtf(a1 * sc) : INFINITY;
    sdist[c0 + 2][dn] = ok ? sqrtf(a2 * sc) : INFINITY;
    sdist[c0 + 3][dn] = ok ? sqrtf(a3 * sc) : INFINITY;
  }
  __syncthreads();

  // ---- selection: wave w handles channel w ----
  float dvr[NU];
#pragma unroll
  for (int u = 0; u < NU; ++u) dvr[u] = sdist[w][u * 64 + lane];

  float sum = 0.f;
  int cn = 0;
#pragma unroll
  for (int k = 0; k < KK; ++k) {
    float g = dvr[0];
#pragma unroll
    for (int u = 1; u < NU; ++u) g = fminf(g, dvr[u]);
#pragma unroll
    for (int off = 32; off > 0; off >>= 1) g = fminf(g, __shfl_xor(g, off));
    if (g < INFINITY) {  // wave-uniform
      int jloc = 0x7FFFFFFF;
#pragma unroll
      for (int u = NU - 1; u >= 0; --u)
        if (dvr[u] == g) jloc = u * 64 + lane;  // lowest u => lowest index
      int jg = jloc;
#pragma unroll
      for (int off = 32; off > 0; off >>= 1) jg = min(jg, __shfl_xor(jg, off));
      const int jgs = __builtin_amdgcn_readfirstlane(jg);
      const int tu = jgs >> 6, tl = jgs & 63;
#pragma unroll
      for (int u = 0; u < NU; ++u)
        if (u == tu) dvr[u] = (lane == tl) ? INFINITY : dvr[u];
      sum += xd[((size_t)16 * NN + jgs) * CC + w];  // ascending (d,j) order
      ++cn;
    }
  }
  if (lane == 0) out[i * CC + w] = (cn > 0) ? sum / (float)cn : colmean[w];
}

// ---------------------------------------------------------------------------
extern "C" void kernel_launch(void* const* d_in, const int* in_sizes, int n_in,
                              void* d_out, int out_size, void* d_ws, size_t ws_size,
                              hipStream_t stream) {
  const float* x_all = (const float*)d_in[0];  // [17, 2048, 9] f32
  const int* mask = (const int*)d_in[1];       // [17, 2048] i32
  float* out = (float*)d_out;                  // [2048, 8] f32

  char* ws = (char*)d_ws;
  float* xd = (float*)ws;
  unsigned* pm = (unsigned*)(ws + XD_BYTES);
  int* dlist = (int*)(ws + XD_BYTES + NN * 4);
  unsigned* pmd = (unsigned*)(ws + XD_BYTES + NN * 8);
  int* qlist = (int*)(ws + XD_BYTES + NN * 12);
  float* colmean = (float*)(ws + XD_BYTES + NN * 16);
  int* cnts = (int*)(ws + XD_BYTES + NN * 16 + CC * 4);

  prep_kernel<<<1, 1024, 0, stream>>>(x_all, mask, pm, dlist, pmd, qlist, colmean, cnts, out);
  transpose_kernel<<<(T1 * NN * CC + 255) / 256, 256, 0, stream>>>(x_all, dlist, cnts, xd);
  knn_main<<<NQCAP, 512, 0, stream>>>(x_all, xd, pm, pmd, qlist, cnts, colmean, out);
}

// Round 6
// 45.376 us; speedup vs baseline: 6.9744x; 1.0404x over previous
//
#include <hip/hip_runtime.h>
#include <math.h>

#define T1 17
#define NN 2048
#define DIN 9
#define CC 8
#define KK 5
#define NSTR 5                 // donor streams per thread (512-thr block)
#define NDCAP (NSTR * 256)     // 1280 donor slots (E[ndon]=1024, +11 sigma)
#define NQCAP 1280             // query slots (nq = 2048 - ndon <= 1280)
#define LPAD (NDCAP + 8)
#define NU (NDCAP / 64)        // 20 cached distances per lane

#define XD_BYTES (T1 * NN * CC * 4)

// ---------------------------------------------------------------------------
// Prep (1 block x 1024): bitmasks, ordered compaction of donors (present at
// t=16) AND queries (missing at t=16), colmean, and passthrough output rows.
__global__ __launch_bounds__(1024) void prep_kernel(
    const float* __restrict__ x_all, const int* __restrict__ mask,
    unsigned* __restrict__ pm, int* __restrict__ dlist,
    unsigned* __restrict__ pmd, int* __restrict__ qlist,
    float* __restrict__ colmean, int* __restrict__ cnts,
    float* __restrict__ out) {
  __shared__ unsigned long long dbal[32];
  __shared__ int dpre[33], qpre[33];
  __shared__ float wsum[16][CC];
  const int tid = threadIdx.x;
  const int lane = tid & 63, w = tid >> 6;  // w in [0,16)

  unsigned m0 = 0, m1 = 0;
#pragma unroll
  for (int t = 0; t < T1; ++t) {
    m0 |= (mask[t * NN + tid] == 0 ? 1u : 0u) << t;
    m1 |= (mask[t * NN + tid + 1024] == 0 ? 1u : 0u) << t;
  }
  pm[tid] = m0;
  pm[tid + 1024] = m1;
  const bool v0 = (m0 >> 16) & 1u, v1 = (m1 >> 16) & 1u;
  const unsigned long long b0 = __ballot(v0), b1 = __ballot(v1);
  if (lane == 0) { dbal[w] = b0; dbal[16 + w] = b1; }

  // passthrough writes + colmean partials
  float s[CC];
#pragma unroll
  for (int c = 0; c < CC; ++c) s[c] = 0.f;
  if (v0) {
    const float* row = x_all + ((size_t)16 * NN + tid) * DIN;
#pragma unroll
    for (int c = 0; c < CC; ++c) { const float v = row[c]; s[c] = v; out[tid * CC + c] = v; }
  }
  if (v1) {
    const float* row = x_all + ((size_t)16 * NN + tid + 1024) * DIN;
#pragma unroll
    for (int c = 0; c < CC; ++c) { const float v = row[c]; s[c] += v; out[(tid + 1024) * CC + c] = v; }
  }
#pragma unroll
  for (int off = 32; off > 0; off >>= 1) {
#pragma unroll
    for (int c = 0; c < CC; ++c) s[c] += __shfl_down(s[c], off);
  }
  if (lane == 0) {
#pragma unroll
    for (int c = 0; c < CC; ++c) wsum[w][c] = s[c];
  }
  __syncthreads();

  if (tid == 0) {
    int a = 0, b = 0;
    for (int g = 0; g < 32; ++g) {
      dpre[g] = a;
      qpre[g] = b;
      const int p = (int)__popcll(dbal[g]);
      a += p;
      b += 64 - p;
    }
    dpre[32] = a;
    qpre[32] = b;
    cnts[0] = a;  // ndon
    cnts[1] = b;  // nq
  }
  __syncthreads();

  const unsigned long long ltm = (1ull << lane) - 1ull;  // lane 0 -> 0
  if (v0) {
    const int p = dpre[w] + (int)__popcll(b0 & ltm);
    dlist[p] = tid; pmd[p] = m0;
  } else {
    const int p = qpre[w] + (int)__popcll((~b0) & ltm);
    qlist[p] = tid;
  }
  if (v1) {
    const int p = dpre[16 + w] + (int)__popcll(b1 & ltm);
    dlist[p] = tid + 1024; pmd[p] = m1;
  } else {
    const int p = qpre[16 + w] + (int)__popcll((~b1) & ltm);
    qlist[p] = tid + 1024;
  }

  if (tid < CC) {
    float tot = 0.f;
#pragma unroll
    for (int ww = 0; ww < 16; ++ww) tot += wsum[ww][tid];
    colmean[tid] = tot / fmaxf((float)dpre[32], 1.f);
  }
}

// ---------------------------------------------------------------------------
// Pack donor data: xd[t][dn][c] = x_all[t][dlist[dn]][c]
__global__ void transpose_kernel(const float* __restrict__ x_all,
                                 const int* __restrict__ dlist,
                                 const int* __restrict__ cnts,
                                 float* __restrict__ xd) {
  const int u = blockIdx.x * 256 + threadIdx.x;
  if (u >= T1 * NN * CC) return;
  const int t = u / (NN * CC);
  const int rem = u % (NN * CC);
  const int dn = rem >> 3;
  const int c = rem & 7;
  if (dn < cnts[0]) xd[u] = x_all[((size_t)t * NN + dlist[dn]) * DIN + c];
}

// ---------------------------------------------------------------------------
// Main: one block (512 thr) per QUERY row (compacted). Sparse t-walk over
// mi's set bits, TWO bits per iteration (odd tail padded with t=16 whose
// flag is provably 0), 5 streams unrolled inside -> 10 independent float4
// loads in flight. Selection: wave w = channel w, register-cached 20 values,
// 5 extraction rounds (bit-exact, lowest-index ties == numpy top_k).
__global__ __launch_bounds__(512, 3) void knn_main(
    const float* __restrict__ x_all, const float* __restrict__ xd,
    const unsigned* __restrict__ pm, const unsigned* __restrict__ pmd,
    const int* __restrict__ qlist, const int* __restrict__ cnts,
    const float* __restrict__ colmean, float* __restrict__ out) {
  __shared__ float sdist[CC][LPAD];  // 41,216 B
  __shared__ float qlds[T1][CC];     // row 16 = zeros (pad; flag always 0)
  __shared__ float rcp17[32];
  const int nq = cnts[1];
  const int bid = blockIdx.x;
  if (bid >= nq) return;
  const int i = qlist[bid];          // missing at t=16 by construction
  const int ndon = cnts[0];
  const unsigned mi = pm[i];         // bit 16 == 0
  const int tid = threadIdx.x;

  if (tid < 32) rcp17[tid] = 17.f / (float)tid;  // [0] = inf, guarded
  if (tid < 16 * CC)
    qlds[tid >> 3][tid & 7] = x_all[((size_t)(tid >> 3) * NN + i) * DIN + (tid & 7)];
  if (tid >= 16 * CC && tid < 17 * CC) qlds[16][tid & 7] = 0.f;
  __syncthreads();

  const int qd = tid & 1;       // channel half -> c0..c0+3
  const int c0 = qd * 4;
  const int dg = tid >> 1;      // [0,256)
  const int lane = tid & 63;
  const int w = tid >> 6;       // wave id = channel

  // ---- distance phase ----
  float a0[NSTR], a1[NSTR], a2[NSTR], a3[NSTR];
  unsigned ms[NSTR];
#pragma unroll
  for (int s = 0; s < NSTR; ++s) {
    const int dn = dg + 256 * s;
    ms[s] = (dn < ndon) ? (mi & pmd[dn]) : 0u;
    a0[s] = a1[s] = a2[s] = a3[s] = 0.f;
  }
  const int nstr_act = (ndon + 255) >> 8;  // block-uniform live stream count

  unsigned tm = mi & 0xFFFFu;
  while (tm) {
    const int t0 = __ffs(tm) - 1;
    tm &= tm - 1u;
    const int t1 = tm ? (__ffs(tm) - 1) : 16;  // pad: flag at t=16 is 0
    tm = tm ? (tm & (tm - 1u)) : 0u;
    const float4 qv0 = *(const float4*)&qlds[t0][c0];
    const float4 qv1 = *(const float4*)&qlds[t1][c0];
#pragma unroll
    for (int s = 0; s < NSTR; ++s) {
      if (s < nstr_act) {
        const int dn = dg + 256 * s;
        const float4 dv0 = *(const float4*)&xd[((size_t)t0 * NN + dn) * CC + c0];
        const float4 dv1 = *(const float4*)&xd[((size_t)t1 * NN + dn) * CC + c0];
        const float fl0 = (float)((ms[s] >> t0) & 1u);
        const float fl1 = (float)((ms[s] >> t1) & 1u);
        float e;
        e = qv0.x - dv0.x; a0[s] = fmaf(e * e, fl0, a0[s]);
        e = qv0.y - dv0.y; a1[s] = fmaf(e * e, fl0, a1[s]);
        e = qv0.z - dv0.z; a2[s] = fmaf(e * e, fl0, a2[s]);
        e = qv0.w - dv0.w; a3[s] = fmaf(e * e, fl0, a3[s]);
        e = qv1.x - dv1.x; a0[s] = fmaf(e * e, fl1, a0[s]);
        e = qv1.y - dv1.y; a1[s] = fmaf(e * e, fl1, a1[s]);
        e = qv1.z - dv1.z; a2[s] = fmaf(e * e, fl1, a2[s]);
        e = qv1.w - dv1.w; a3[s] = fmaf(e * e, fl1, a3[s]);
      }
    }
  }

#pragma unroll
  for (int s = 0; s < NSTR; ++s) {
    const int dn = dg + 256 * s;
    const int cnt = __popc(ms[s]);
    const float sc = rcp17[cnt & 31];
    const bool ok = cnt > 0;
    sdist[c0 + 0][dn] = ok ? sqrtf(a0[s] * sc) : INFINITY;
    sdist[c0 + 1][dn] = ok ? sqrtf(a1[s] * sc) : INFINITY;
    sdist[c0 + 2][dn] = ok ? sqrtf(a2[s] * sc) : INFINITY;
    sdist[c0 + 3][dn] = ok ? sqrtf(a3[s] * sc) : INFINITY;
  }
  __syncthreads();

  // ---- selection: wave w handles channel w ----
  float dvr[NU];
#pragma unroll
  for (int u = 0; u < NU; ++u) dvr[u] = sdist[w][u * 64 + lane];

  float sum = 0.f;
  int cn = 0;
#pragma unroll
  for (int k = 0; k < KK; ++k) {
    float g = dvr[0];
#pragma unroll
    for (int u = 1; u < NU; ++u) g = fminf(g, dvr[u]);
#pragma unroll
    for (int off = 32; off > 0; off >>= 1) g = fminf(g, __shfl_xor(g, off));
    if (g < INFINITY) {  // wave-uniform
      int jloc = 0x7FFFFFFF;
#pragma unroll
      for (int u = NU - 1; u >= 0; --u)
        if (dvr[u] == g) jloc = u * 64 + lane;  // lowest u => lowest index
      int jg = jloc;
#pragma unroll
      for (int off = 32; off > 0; off >>= 1) jg = min(jg, __shfl_xor(jg, off));
      const int jgs = __builtin_amdgcn_readfirstlane(jg);
      const int tu = jgs >> 6, tl = jgs & 63;
#pragma unroll
      for (int u = 0; u < NU; ++u)
        if (u == tu) dvr[u] = (lane == tl) ? INFINITY : dvr[u];
      sum += xd[((size_t)16 * NN + jgs) * CC + w];  // ascending (d,j) order
      ++cn;
    }
  }
  if (lane == 0) out[i * CC + w] = (cn > 0) ? sum / (float)cn : colmean[w];
}

// ---------------------------------------------------------------------------
extern "C" void kernel_launch(void* const* d_in, const int* in_sizes, int n_in,
                              void* d_out, int out_size, void* d_ws, size_t ws_size,
                              hipStream_t stream) {
  const float* x_all = (const float*)d_in[0];  // [17, 2048, 9] f32
  const int* mask = (const int*)d_in[1];       // [17, 2048] i32
  float* out = (float*)d_out;                  // [2048, 8] f32

  char* ws = (char*)d_ws;
  float* xd = (float*)ws;
  unsigned* pm = (unsigned*)(ws + XD_BYTES);
  int* dlist = (int*)(ws + XD_BYTES + NN * 4);
  unsigned* pmd = (unsigned*)(ws + XD_BYTES + NN * 8);
  int* qlist = (int*)(ws + XD_BYTES + NN * 12);
  float* colmean = (float*)(ws + XD_BYTES + NN * 16);
  int* cnts = (int*)(ws + XD_BYTES + NN * 16 + CC * 4);

  prep_kernel<<<1, 1024, 0, stream>>>(x_all, mask, pm, dlist, pmd, qlist, colmean, cnts, out);
  transpose_kernel<<<(T1 * NN * CC + 255) / 256, 256, 0, stream>>>(x_all, dlist, cnts, xd);
  knn_main<<<NQCAP, 512, 0, stream>>>(x_all, xd, pm, pmd, qlist, cnts, colmean, out);
}